// Round 1
// baseline (16157.523 us; speedup 1.0000x reference)
//
#include <hip/hip_runtime.h>

typedef _Float16 f16;
typedef _Float16 f16x2 __attribute__((ext_vector_type(2)));
typedef _Float16 f16x8 __attribute__((ext_vector_type(8)));
typedef float    f32x4 __attribute__((ext_vector_type(4)));
typedef unsigned int u32;

#define DEVI static __device__ __forceinline__

static constexpr int LDT = 40;    // lds row stride (halves) for 64x32 tiles (+8 pad)
static constexpr int LDA = 264;   // lds row stride for 64x256 resident A tiles

DEVI float sigf(float x){ return 1.f/(1.f + __expf(-x)); }
DEVI float tanh_c(float x){
  x = fminf(fmaxf(x, -15.f), 15.f);
  float e = __expf(2.f*x);
  return (e - 1.f)/(e + 1.f);
}
DEVI u32 pack2(float a, float b){ f16x2 h; h.x=(f16)a; h.y=(f16)b; return __builtin_bit_cast(u32, h); }
DEVI float dot2u(u32 w, u32 h, float c){
#if __has_builtin(__builtin_amdgcn_fdot2)
  return __builtin_amdgcn_fdot2(__builtin_bit_cast(f16x2,w), __builtin_bit_cast(f16x2,h), c, false);
#else
  f16x2 a=__builtin_bit_cast(f16x2,w), b=__builtin_bit_cast(f16x2,h);
  return c + (float)a.x*(float)b.x + (float)a.y*(float)b.y;
#endif
}
DEVI float wmax16(float v){
  #pragma unroll
  for (int m=1;m<16;m<<=1) v = fmaxf(v, __shfl_xor(v, m, 64));
  return v;
}
DEVI float wsum16(float v){
  #pragma unroll
  for (int m=1;m<16;m<<=1) v += __shfl_xor(v, m, 64);
  return v;
}
DEVI f16x8 frag_ld(const f16* p){ return *(const f16x8*)p; }
DEVI void stage_tile(const f16* src, int ld, f16* dst){
  int tid = threadIdx.x; int row = tid>>2, qq = tid&3;
  *(f16x8*)(dst + row*LDT + qq*8) = *(const f16x8*)(src + (size_t)row*ld + qq*8);
}
#define ZERO4(acc) { f32x4 _z = {0.f,0.f,0.f,0.f}; acc[0]=_z; acc[1]=_z; acc[2]=_z; acc[3]=_z; }

// 64x64 NT MFMA tile: A (64 x K, row-major lda), B^T (64 x K, row-major ldb)
DEVI void gemm64(const f16* A, int lda, const f16* Bm, int ldb, int K,
                 f16* lA, f16* lB, f32x4 acc[4]){
  const int lane = threadIdx.x & 63, wv = threadIdx.x >> 6;
  const int l15 = lane & 15, kq = lane >> 4;
  for (int k0=0; k0<K; k0+=32){
    __syncthreads();
    stage_tile(A + k0, lda, lA);
    stage_tile(Bm + k0, ldb, lB);
    __syncthreads();
    f16x8 af = frag_ld(lA + (16*wv + l15)*LDT + kq*8);
    #pragma unroll
    for (int nt=0; nt<4; nt++){
      f16x8 bf = frag_ld(lB + (16*nt + l15)*LDT + kq*8);
      acc[nt] = __builtin_amdgcn_mfma_f32_16x16x32_f16(af, bf, acc[nt], 0,0,0);
    }
  }
}

// ---------------- small prep kernels ----------------
__global__ void k_cvt(const float* __restrict__ s, f16* __restrict__ d, int n){
  int i = blockIdx.x*256 + threadIdx.x;
  if (i < n) d[i] = (f16)s[i];
}
// gconv (K,Fi,Fo) -> gcT (Fo, K*Fi)
__global__ void k_gconvT(const float* __restrict__ s, f16* __restrict__ d){
  int id = blockIdx.x;            // k*256+fi : 1280
  int fo = threadIdx.x;           // 256
  d[(size_t)fo*1280 + id] = (f16)s[(size_t)id*256 + fo];
}
// gdecode (F,V) -> gdT (VP=2048, F) zero-padded rows
__global__ void k_gdecT(const float* __restrict__ s, f16* __restrict__ d){
  int v = blockIdx.x, f = threadIdx.x;    // 2048 x 256
  f16 val = (f16)0.f;
  if (v < 2000) val = (f16)s[(size_t)f*2000 + v];
  d[(size_t)v*256 + f] = val;
}
// e_pad[b][p][f] = p in [2,514) ? tanh(gembed[xs[b][p-2]][f]) : 0
__global__ void k_epad(const int* __restrict__ xs, const float* __restrict__ gemb, f16* __restrict__ epad){
  int id = blockIdx.x;            // b*516+p
  int f = threadIdx.x;
  int b = id / 516, p = id % 516;
  float v = 0.f;
  if (p >= 2 && p < 514){ int idx = xs[b*512 + p - 2]; v = tanh_c(gemb[(size_t)idx*256 + f]); }
  epad[(size_t)id*256 + f] = (f16)v;
}
// enc/dec embeddings with <P mask
__global__ void k_embx(const int* __restrict__ xs, const int* __restrict__ ys,
                       const float* __restrict__ eemb, const float* __restrict__ demb,
                       f16* __restrict__ xo, f16* __restrict__ yo){
  int id = blockIdx.x; int f = threadIdx.x;  // 2*32*512 blocks x 128
  bool dec = id >= 32*512; int id2 = dec ? id - 32*512 : id;
  int idx = dec ? ys[id2] : xs[id2];
  if (idx < 4) idx = 0;
  const float* src = (dec ? demb : eemb) + (size_t)idx*128;
  (dec ? yo : xo)[(size_t)id2*128 + f] = (f16)src[f];
}

// ---------------- GEMM kernels ----------------
__global__ __launch_bounds__(256,4) void k_conv(const f16* __restrict__ epad, const f16* __restrict__ gcT, f16* __restrict__ tf){
  __shared__ f16 lA[64*LDT], lB[64*LDT];
  const int m0 = blockIdx.x*64, n0 = blockIdx.y*64;
  const int b = m0 >> 9, n = m0 & 511;
  f32x4 acc[4]; ZERO4(acc);
  gemm64(epad + ((size_t)b*516 + n)*256, 256, gcT + (size_t)n0*1280, 1280, 1280, lA, lB, acc);
  const int lane=threadIdx.x&63, wv=threadIdx.x>>6, l15=lane&15, kq=lane>>4;
  #pragma unroll
  for (int nt=0;nt<4;nt++)
    #pragma unroll
    for (int r=0;r<4;r++)
      tf[(size_t)(m0 + 16*wv + 4*kq + r)*256 + n0 + nt*16 + l15] = (f16)tanh_c(acc[nt][r]);
}

__global__ __launch_bounds__(256,4) void k_u(const f16* __restrict__ X, const f16* __restrict__ Wih,
                                             const float* __restrict__ bias, f16* __restrict__ U){
  __shared__ f16 lA[64*LDT], lB[64*LDT];
  const int m0 = blockIdx.x*64, n0 = blockIdx.y*64;
  f32x4 acc[4]; ZERO4(acc);
  gemm64(X + (size_t)m0*128, 128, Wih + (size_t)n0*128, 128, 128, lA, lB, acc);
  const int lane=threadIdx.x&63, wv=threadIdx.x>>6, l15=lane&15, kq=lane>>4;
  #pragma unroll
  for (int nt=0;nt<4;nt++){
    float bv = bias[n0 + nt*16 + l15];
    #pragma unroll
    for (int r=0;r<4;r++)
      U[(size_t)(m0 + 16*wv + 4*kq + r)*1024 + n0 + nt*16 + l15] = (f16)(acc[nt][r] + bv);
  }
}

__global__ __launch_bounds__(256,4) void k_th(const f16* __restrict__ henh, const f16* __restrict__ Tf, f16* __restrict__ Th){
  __shared__ f16 lA[64*LDT], lB[64*LDT];
  const int m0 = blockIdx.x*64, n0 = blockIdx.y*64;
  f32x4 acc[4]; ZERO4(acc);
  gemm64(henh + (size_t)m0*512, 512, Tf + (size_t)n0*512, 512, 512, lA, lB, acc);
  const int lane=threadIdx.x&63, wv=threadIdx.x>>6, l15=lane&15, kq=lane>>4;
  #pragma unroll
  for (int nt=0;nt<4;nt++)
    #pragma unroll
    for (int r=0;r<4;r++)
      Th[(size_t)(m0 + 16*wv + 4*kq + r)*256 + n0 + nt*16 + l15] = (f16)acc[nt][r];
}

// pass1: online row-max + sum-exp of logits = tf @ gdT^T over N=2048 (cols>=2000 masked)
__global__ __launch_bounds__(256,2) void k_pass1(const f16* __restrict__ tf, const f16* __restrict__ gdT,
                                                 float* __restrict__ mxp, float* __restrict__ sep){
  __shared__ f16 lA[64*LDA];
  __shared__ f16 lB[64*LDT];
  __shared__ float mx_s[64], se_s[64];
  const int mt = blockIdx.x, ns = blockIdx.y;
  const int tid = threadIdx.x, lane=tid&63, wv=tid>>6, l15=lane&15, kq=lane>>4;
  {
    const f16* A = tf + (size_t)mt*64*256;
    int row = tid>>2, qq = tid&3;
    #pragma unroll
    for (int c=0;c<8;c++)
      *(f16x8*)(lA + row*LDA + c*32 + qq*8) = *(const f16x8*)(A + (size_t)row*256 + c*32 + qq*8);
  }
  if (tid < 64){ mx_s[tid] = -1e30f; se_s[tid] = 0.f; }
  __syncthreads();
  for (int nc=0; nc<8; nc++){
    const int nbase = ns*512 + nc*64;
    const f16* Bm = gdT + (size_t)nbase*256;
    f32x4 acc[4]; ZERO4(acc);
    for (int k0=0; k0<256; k0+=32){
      __syncthreads();
      stage_tile(Bm + k0, 256, lB);
      __syncthreads();
      f16x8 af = frag_ld(lA + (16*wv + l15)*LDA + k0 + kq*8);
      #pragma unroll
      for (int nt=0; nt<4; nt++){
        f16x8 bf = frag_ld(lB + (16*nt + l15)*LDT + kq*8);
        acc[nt] = __builtin_amdgcn_mfma_f32_16x16x32_f16(af, bf, acc[nt], 0,0,0);
      }
    }
    #pragma unroll
    for (int r=0;r<4;r++){
      float av[4]; float cm = -1e30f;
      #pragma unroll
      for (int nt=0;nt<4;nt++){
        int gcol = nbase + nt*16 + l15;
        float a = (gcol < 2000) ? acc[nt][r] : -1e30f;
        av[nt] = a; cm = fmaxf(cm, a);
      }
      cm = wmax16(cm);
      int rr = 16*wv + 4*kq + r;
      float old = mx_s[rr];
      float nm = fmaxf(old, cm);
      float ss = 0.f;
      #pragma unroll
      for (int nt=0;nt<4;nt++) ss += __expf(av[nt] - nm);
      ss = wsum16(ss);
      if (l15 == 0){
        se_s[rr] = se_s[rr]*__expf(old - nm) + ss;
        mx_s[rr] = nm;
      }
    }
  }
  __syncthreads();
  if (tid < 64){
    mxp[(size_t)ns*16384 + mt*64 + tid] = mx_s[tid];
    sep[(size_t)ns*16384 + mt*64 + tid] = se_s[tid];
  }
}

__global__ void k_comb1(const float* __restrict__ mxp, const float* __restrict__ sep,
                        float* __restrict__ mx, float* __restrict__ se){
  int m = blockIdx.x*256 + threadIdx.x;
  float best = -1e30f;
  #pragma unroll
  for (int k=0;k<4;k++) best = fmaxf(best, mxp[(size_t)k*16384 + m]);
  float s = 0.f;
  #pragma unroll
  for (int k=0;k<4;k++) s += sep[(size_t)k*16384 + m] * __expf(mxp[(size_t)k*16384 + m] - best);
  mx[m] = best; se[m] = s;
}

// pass2: scoresT[b][j][i] = exp(logit(i, ys[b][j]) - mx)/se  via gathered-row GEMM
__global__ __launch_bounds__(256,4) void k_pass2(const f16* __restrict__ tf, const f16* __restrict__ gdT,
                                                 const int* __restrict__ ys, const float* __restrict__ mx,
                                                 const float* __restrict__ se, f16* __restrict__ scT){
  __shared__ f16 lA[64*LDT], lB[64*LDT];
  __shared__ int jv[64];
  const int it = blockIdx.x, jt = blockIdx.y, b = blockIdx.z;
  const int tid = threadIdx.x, lane=tid&63, wv=tid>>6, l15=lane&15, kq=lane>>4;
  if (tid<64) jv[tid] = ys[b*512 + jt*64 + tid];
  const f16* A = tf + ((size_t)b*512 + it*64)*256;
  f32x4 acc[4]; ZERO4(acc);
  for (int k0=0;k0<256;k0+=32){
    __syncthreads();
    stage_tile(A + k0, 256, lA);
    { int row=tid>>2, qq=tid&3;
      *(f16x8*)(lB + row*LDT + qq*8) = *(const f16x8*)(gdT + (size_t)jv[row]*256 + k0 + qq*8); }
    __syncthreads();
    f16x8 af = frag_ld(lA + (16*wv+l15)*LDT + kq*8);
    #pragma unroll
    for (int nt=0;nt<4;nt++){
      f16x8 bf = frag_ld(lB + (16*nt+l15)*LDT + kq*8);
      acc[nt] = __builtin_amdgcn_mfma_f32_16x16x32_f16(af, bf, acc[nt], 0,0,0);
    }
  }
  float mxv[4], rsev[4];
  #pragma unroll
  for (int r=0;r<4;r++){
    int i_ = it*64 + 16*wv + 4*kq + r;
    mxv[r] = mx[b*512 + i_];
    rsev[r] = 1.f / se[b*512 + i_];
  }
  #pragma unroll
  for (int nt=0;nt<4;nt++){
    int j_ = jt*64 + nt*16 + l15;
    #pragma unroll
    for (int r=0;r<4;r++){
      int i_ = it*64 + 16*wv + 4*kq + r;
      scT[((size_t)b*512 + j_)*512 + i_] = (f16)(__expf(acc[nt][r] - mxv[r]) * rsev[r]);
    }
  }
}

// fused eij -> softmax over i -> <scores,align> -> partials (i split in 2)
__global__ __launch_bounds__(256,2) void k_final(const f16* __restrict__ hdec, const f16* __restrict__ Th,
                                                 const f16* __restrict__ scT,
                                                 float* __restrict__ pmx, float* __restrict__ pden, float* __restrict__ pnum){
  __shared__ f16 lA[64*LDA];
  __shared__ f16 lB[64*LDT];
  __shared__ float mx_s[64], den_s[64], num_s[64];
  const int is = blockIdx.x, jt = blockIdx.y, b = blockIdx.z;
  const int tid = threadIdx.x, lane=tid&63, wv=tid>>6, l15=lane&15, kq=lane>>4;
  {
    const f16* A = hdec + ((size_t)b*512 + jt*64)*256;
    int row = tid>>2, qq = tid&3;
    #pragma unroll
    for (int c=0;c<8;c++)
      *(f16x8*)(lA + row*LDA + c*32 + qq*8) = *(const f16x8*)(A + (size_t)row*256 + c*32 + qq*8);
  }
  if (tid<64){ mx_s[tid]=-1e30f; den_s[tid]=0.f; num_s[tid]=0.f; }
  __syncthreads();
  for (int ic=0; ic<4; ic++){
    const int i0 = is*256 + ic*64;
    const f16* Bm = Th + ((size_t)b*512 + i0)*256;
    f32x4 acc[4]; ZERO4(acc);
    for (int k0=0;k0<256;k0+=32){
      __syncthreads();
      stage_tile(Bm + k0, 256, lB);
      __syncthreads();
      f16x8 af = frag_ld(lA + (16*wv+l15)*LDA + k0 + kq*8);
      #pragma unroll
      for (int nt=0;nt<4;nt++){
        f16x8 bf = frag_ld(lB + (16*nt+l15)*LDT + kq*8);
        acc[nt] = __builtin_amdgcn_mfma_f32_16x16x32_f16(af, bf, acc[nt], 0,0,0);
      }
    }
    #pragma unroll
    for (int r=0;r<4;r++){
      int jl = 16*wv + 4*kq + r;
      float av[4]; float cm=-1e30f;
      #pragma unroll
      for (int nt=0;nt<4;nt++){ av[nt]=acc[nt][r]; cm=fmaxf(cm,av[nt]); }
      cm = wmax16(cm);
      float old = mx_s[jl], nm = fmaxf(old, cm);
      float ds=0.f, nsum=0.f;
      const size_t srow = ((size_t)b*512 + jt*64 + jl)*512;
      #pragma unroll
      for (int nt=0;nt<4;nt++){
        float e = __expf(av[nt]-nm);
        float sc = (float)scT[srow + i0 + nt*16 + l15];
        ds += e; nsum += sc*e;
      }
      ds = wsum16(ds); nsum = wsum16(nsum);
      if (l15==0){
        float fac = __expf(old-nm);
        den_s[jl] = den_s[jl]*fac + ds;
        num_s[jl] = num_s[jl]*fac + nsum;
        mx_s[jl] = nm;
      }
    }
  }
  __syncthreads();
  if (tid<64){
    size_t idx = (((size_t)b*512) + jt*64 + tid)*2 + is;
    pmx[idx]=mx_s[tid]; pden[idx]=den_s[tid]; pnum[idx]=num_s[tid];
  }
}

__global__ void k_comb2(const float* __restrict__ pmx, const float* __restrict__ pden,
                        const float* __restrict__ pnum, float* __restrict__ out){
  const int b = blockIdx.x, j = threadIdx.x;    // 32 x 512
  size_t base = ((size_t)b*512 + j)*2;
  float m0=pmx[base], m1=pmx[base+1];
  float m = fmaxf(m0,m1);
  float e0=__expf(m0-m), e1=__expf(m1-m);
  float den = pden[base]*e0 + pden[base+1]*e1;
  float num = pnum[base]*e0 + pnum[base+1]*e1;
  float lp = __logf(num) - __logf(den);
  __shared__ float red[512];
  red[j] = lp;
  __syncthreads();
  for (int st=256; st>0; st>>=1){ if (j<st) red[j]+=red[j+st]; __syncthreads(); }
  if (j==0) atomicAdd(out, -red[0]);
}

// ---------------- LSTM: 8-WG clusters, weights in VGPRs, cross-CU h exchange ----------------
__global__ __launch_bounds__(256,2) void k_lstm(
    const f16* __restrict__ U, const f16* __restrict__ Whh,
    u32* __restrict__ hout, float* __restrict__ hTcT,
    u32* __restrict__ hx, u32* __restrict__ flags, u32* __restrict__ hdec0,
    int nseq, int nsteps, int mode)
{
  const int tid = threadIdx.x;
  const int q = blockIdx.x / nseq;       // 0..7 : which 1/8 of rows
  const int s = blockIdx.x % nseq;       // cluster (sequence) id
  int dir = 0, b = s;
  if (mode == 0){ dir = (s >= 32) ? 1 : 0; b = s & 31; }

  const int r  = tid >> 1;               // local z-row 0..127
  const int kh = tid & 1;                // K half
  const int grow = ((r >> 5) << 8) + (q << 5) + (r & 31);  // gate*256 + q*32 + jj

  uint4 wv[16];                          // 128 f16 weights = 64 VGPRs
  {
    const uint4* wp = (const uint4*)(Whh + (size_t)grow*256 + kh*128);
    #pragma unroll
    for (int i=0;i<16;i++) wv[i] = wp[i];
  }

  __shared__ __align__(16) u32 h2[128];  // h as packed f16x2
  __shared__ float zl[128];

  u32* myhx = hx + (size_t)s*256;        // [2][128]
  u32* myfl = flags + (size_t)s*128;     // 8 flags, 64B apart

  float cst = 0.f;
  if (mode == 0){
    if (tid < 128) h2[tid] = 0u;
  } else {
    if (tid < 128){
      float a = hTcT[(size_t)b*512 + 2*tid];
      float c2 = hTcT[(size_t)b*512 + 2*tid + 1];
      h2[tid] = pack2(a, c2);
    }
    if (tid < 32) cst = hTcT[(size_t)b*512 + 256 + q*32 + tid];
  }
  __syncthreads();

  for (int t=0; t<nsteps; ++t){
    if (t > 0){
      if (tid < 8){
        while (__hip_atomic_load(&myfl[tid*16], __ATOMIC_ACQUIRE, __HIP_MEMORY_SCOPE_AGENT) < (u32)t)
          __builtin_amdgcn_s_sleep(1);
      }
      __syncthreads();
      if (tid < 128)
        h2[tid] = __hip_atomic_load(&myhx[(t&1)*128 + tid], __ATOMIC_RELAXED, __HIP_MEMORY_SCOPE_AGENT);
      __syncthreads();
    }

    float acc = 0.f;
    {
      const uint4* hp = ((const uint4*)h2) + kh*16;
      #pragma unroll
      for (int a=0;a<16;a++){
        uint4 hh = hp[a];
        acc = dot2u(wv[a].x, hh.x, acc);
        acc = dot2u(wv[a].y, hh.y, acc);
        acc = dot2u(wv[a].z, hh.z, acc);
        acc = dot2u(wv[a].w, hh.w, acc);
      }
    }
    acc += __shfl_xor(acc, 1, 64);

    const int tpos = dir ? (nsteps - 1 - t) : t;
    if (kh == 0)
      zl[r] = acc + (float)U[((size_t)b*512 + tpos)*1024 + grow];
    __syncthreads();

    if (tid < 32){
      float ig = sigf(zl[tid]);
      float fg = sigf(zl[32+tid]);
      float gg = tanh_c(zl[64+tid]);
      float og = sigf(zl[96+tid]);
      cst = fg*cst + ig*gg;
      float h = og*tanh_c(cst);
      float hlo = __shfl(h, 2*(tid & 15), 64);
      float hhi = __shfl(h, 2*(tid & 15) + 1, 64);
      if (tid < 16){
        u32 hp2 = pack2(hlo, hhi);
        __hip_atomic_store(&myhx[((t+1)&1)*128 + q*16 + tid], hp2, __ATOMIC_RELAXED, __HIP_MEMORY_SCOPE_AGENT);
        if (mode == 0){
          hout[((size_t)b*512 + tpos)*256 + dir*128 + q*16 + tid] = hp2;   // henh: fwd cols 0:256, bwd 256:512
          if (!dir && t == nsteps-1)
            hdec0[(size_t)b*512*128 + q*16 + tid] = hp2;                   // hdec[b][0] = henc[b][511]
        } else {
          if (t < 511)
            hout[((size_t)b*512 + (t+1))*128 + q*16 + tid] = hp2;          // hdec[b][t+1]
        }
      }
      if (mode == 0 && !dir && t == nsteps-1){
        hTcT[(size_t)b*512 + q*32 + tid] = h;
        hTcT[(size_t)b*512 + 256 + q*32 + tid] = cst;
      }
    }
    __syncthreads();
    if (tid == 0){
      __threadfence();
      __hip_atomic_store(&myfl[q*16], (u32)(t+1), __ATOMIC_RELEASE, __HIP_MEMORY_SCOPE_AGENT);
    }
  }
}

// ---------------- host ----------------
extern "C" void kernel_launch(void* const* d_in, const int* in_sizes, int n_in,
                              void* d_out, int out_size, void* d_ws, size_t ws_size,
                              hipStream_t stream)
{
  (void)in_sizes; (void)n_in; (void)out_size;
  const int*   xs    = (const int*)d_in[0];
  const int*   ys    = (const int*)d_in[1];
  const float* gemb  = (const float*)d_in[2];
  const float* gconv = (const float*)d_in[3];
  const float* gdec  = (const float*)d_in[4];
  const float* eemb  = (const float*)d_in[5];
  const float* demb  = (const float*)d_in[6];
  const float* eWih  = (const float*)d_in[7];
  const float* eWhh  = (const float*)d_in[8];
  const float* eb    = (const float*)d_in[9];
  const float* dWih  = (const float*)d_in[10];
  const float* dWhh  = (const float*)d_in[11];
  const float* db    = (const float*)d_in[12];
  const float* Tm    = (const float*)d_in[13];

  char* wsb = (char*)d_ws;
  size_t off = 0;
  auto take = [&](size_t bytes)->char*{ char* p = wsb + off; off += (bytes + 255) & ~(size_t)255; return p; };
  f16* epad  = (f16*)take((size_t)32*516*256*2);
  f16* tf    = (f16*)take((size_t)32*512*256*2);
  f16* xemb  = (f16*)take((size_t)32*512*128*2);
  f16* yemb  = (f16*)take((size_t)32*512*128*2);
  f16* Uenc  = (f16*)take((size_t)32*512*1024*2);
  f16* Udec  = (f16*)take((size_t)32*512*1024*2);
  f16* henh  = (f16*)take((size_t)32*512*512*2);
  f16* hdec  = (f16*)take((size_t)32*512*256*2);
  f16* Th    = (f16*)take((size_t)32*512*256*2);
  f16* scT   = (f16*)take((size_t)32*512*512*2);
  float* mx  = (float*)take((size_t)16384*4);
  float* se  = (float*)take((size_t)16384*4);
  float* mxp = (float*)take((size_t)4*16384*4);
  float* sep = (float*)take((size_t)4*16384*4);
  float* pmx = (float*)take((size_t)32*512*2*4);
  float* pden= (float*)take((size_t)32*512*2*4);
  float* pnum= (float*)take((size_t)32*512*2*4);
  float* hTcT= (float*)take((size_t)32*512*4);
  f16* Wihe  = (f16*)take((size_t)1024*128*2);
  f16* Wihd  = (f16*)take((size_t)1024*128*2);
  f16* Whhe  = (f16*)take((size_t)1024*256*2);
  f16* Whhd  = (f16*)take((size_t)1024*256*2);
  f16* Tf    = (f16*)take((size_t)256*512*2);
  f16* gcT   = (f16*)take((size_t)256*1280*2);
  f16* gdT   = (f16*)take((size_t)2048*256*2);
  u32* flg   = (u32*)take((size_t)(64*128 + 32*128)*4);
  u32* hxe   = (u32*)take((size_t)64*2*128*4);
  u32* hxd   = (u32*)take((size_t)32*2*128*4);
  if (off > ws_size) return;  // insufficient scratch -> visible as wrong answer
  u32* flgd = flg + 64*128;

  hipMemsetAsync(d_out, 0, sizeof(float), stream);
  hipMemsetAsync(flg, 0, (size_t)(64*128 + 32*128)*4, stream);

  // weight conversions
  k_cvt<<<dim3(512),  256, 0, stream>>>(eWih, Wihe, 1024*128);
  k_cvt<<<dim3(512),  256, 0, stream>>>(dWih, Wihd, 1024*128);
  k_cvt<<<dim3(1024), 256, 0, stream>>>(eWhh, Whhe, 1024*256);
  k_cvt<<<dim3(1024), 256, 0, stream>>>(dWhh, Whhd, 1024*256);
  k_cvt<<<dim3(512),  256, 0, stream>>>(Tm,   Tf,   256*512);
  k_gconvT<<<dim3(1280), 256, 0, stream>>>(gconv, gcT);
  k_gdecT <<<dim3(2048), 256, 0, stream>>>(gdec, gdT);

  // embeddings
  k_epad<<<dim3(32*516), 256, 0, stream>>>(xs, gemb, epad);
  k_embx<<<dim3(2*32*512), 128, 0, stream>>>(xs, ys, eemb, demb, xemb, yemb);

  // G-stack
  k_conv<<<dim3(256,4), 256, 0, stream>>>(epad, gcT, tf);
  k_pass1<<<dim3(256,4), 256, 0, stream>>>(tf, gdT, mxp, sep);
  k_comb1<<<dim3(64), 256, 0, stream>>>(mxp, sep, mx, se);
  k_pass2<<<dim3(8,8,32), 256, 0, stream>>>(tf, gdT, ys, mx, se, scT);

  // LSTM input-gate precompute
  k_u<<<dim3(256,16), 256, 0, stream>>>(xemb, Wihe, eb, Uenc);
  k_u<<<dim3(256,16), 256, 0, stream>>>(yemb, Wihd, db, Udec);

  // recurrences
  k_lstm<<<dim3(512), 256, 0, stream>>>(Uenc, Whhe, (u32*)henh, hTcT, hxe, flg,  (u32*)hdec, 64, 512, 0);
  k_lstm<<<dim3(256), 256, 0, stream>>>(Udec, Whhd, (u32*)hdec, hTcT, hxd, flgd, (u32*)hdec, 32, 511, 1);

  // alignment
  k_th<<<dim3(256,4), 256, 0, stream>>>(henh, Tf, Th);
  k_final<<<dim3(2,8,32), 256, 0, stream>>>(hdec, Th, scT, pmx, pden, pnum);
  k_comb2<<<dim3(32), 512, 0, stream>>>(pmx, pden, pnum, (float*)d_out);
}

// Round 2
// 3959.731 us; speedup vs baseline: 4.0805x; 4.0805x over previous
//
#include <hip/hip_runtime.h>

typedef _Float16 f16;
typedef _Float16 f16x2 __attribute__((ext_vector_type(2)));
typedef _Float16 f16x8 __attribute__((ext_vector_type(8)));
typedef float    f32x4 __attribute__((ext_vector_type(4)));
typedef unsigned int u32;
typedef unsigned short u16;

#define DEVI static __device__ __forceinline__

static constexpr int LDT = 40;    // lds row stride (halves) for 64x32 tiles (+8 pad)
static constexpr int LDA = 264;   // lds row stride for 64x256 resident A tiles

DEVI float sigf(float x){ return 1.f/(1.f + __expf(-x)); }
DEVI float tanh_c(float x){
  x = fminf(fmaxf(x, -15.f), 15.f);
  float e = __expf(2.f*x);
  return (e - 1.f)/(e + 1.f);
}
DEVI float dot2u(u32 w, u32 h, float c){
#if __has_builtin(__builtin_amdgcn_fdot2)
  return __builtin_amdgcn_fdot2(__builtin_bit_cast(f16x2,w), __builtin_bit_cast(f16x2,h), c, false);
#else
  f16x2 a=__builtin_bit_cast(f16x2,w), b=__builtin_bit_cast(f16x2,h);
  return c + (float)a.x*(float)b.x + (float)a.y*(float)b.y;
#endif
}
DEVI float wmax16(float v){
  #pragma unroll
  for (int m=1;m<16;m<<=1) v = fmaxf(v, __shfl_xor(v, m, 64));
  return v;
}
DEVI float wsum16(float v){
  #pragma unroll
  for (int m=1;m<16;m<<=1) v += __shfl_xor(v, m, 64);
  return v;
}
DEVI f16x8 frag_ld(const f16* p){ return *(const f16x8*)p; }
DEVI void stage_tile(const f16* src, int ld, f16* dst){
  int tid = threadIdx.x; int row = tid>>2, qq = tid&3;
  *(f16x8*)(dst + row*LDT + qq*8) = *(const f16x8*)(src + (size_t)row*ld + qq*8);
}
#define ZERO4(acc) { f32x4 _z = {0.f,0.f,0.f,0.f}; acc[0]=_z; acc[1]=_z; acc[2]=_z; acc[3]=_z; }

// 64x64 NT MFMA tile: A (64 x K, row-major lda), B^T (64 x K, row-major ldb)
DEVI void gemm64(const f16* A, int lda, const f16* Bm, int ldb, int K,
                 f16* lA, f16* lB, f32x4 acc[4]){
  const int lane = threadIdx.x & 63, wv = threadIdx.x >> 6;
  const int l15 = lane & 15, kq = lane >> 4;
  for (int k0=0; k0<K; k0+=32){
    __syncthreads();
    stage_tile(A + k0, lda, lA);
    stage_tile(Bm + k0, ldb, lB);
    __syncthreads();
    f16x8 af = frag_ld(lA + (16*wv + l15)*LDT + kq*8);
    #pragma unroll
    for (int nt=0; nt<4; nt++){
      f16x8 bf = frag_ld(lB + (16*nt + l15)*LDT + kq*8);
      acc[nt] = __builtin_amdgcn_mfma_f32_16x16x32_f16(af, bf, acc[nt], 0,0,0);
    }
  }
}

// ---------------- small prep kernels ----------------
__global__ void k_cvt(const float* __restrict__ s, f16* __restrict__ d, int n){
  int i = blockIdx.x*256 + threadIdx.x;
  if (i < n) d[i] = (f16)s[i];
}
// gconv (K,Fi,Fo) -> gcT (Fo, K*Fi)
__global__ void k_gconvT(const float* __restrict__ s, f16* __restrict__ d){
  int id = blockIdx.x;            // k*256+fi : 1280
  int fo = threadIdx.x;           // 256
  d[(size_t)fo*1280 + id] = (f16)s[(size_t)id*256 + fo];
}
// gdecode (F,V) -> gdT (VP=2048, F) zero-padded rows
__global__ void k_gdecT(const float* __restrict__ s, f16* __restrict__ d){
  int v = blockIdx.x, f = threadIdx.x;    // 2048 x 256
  f16 val = (f16)0.f;
  if (v < 2000) val = (f16)s[(size_t)f*2000 + v];
  d[(size_t)v*256 + f] = val;
}
// e_pad[b][p][f] = p in [2,514) ? tanh(gembed[xs[b][p-2]][f]) : 0
__global__ void k_epad(const int* __restrict__ xs, const float* __restrict__ gemb, f16* __restrict__ epad){
  int id = blockIdx.x;            // b*516+p
  int f = threadIdx.x;
  int b = id / 516, p = id % 516;
  float v = 0.f;
  if (p >= 2 && p < 514){ int idx = xs[b*512 + p - 2]; v = tanh_c(gemb[(size_t)idx*256 + f]); }
  epad[(size_t)id*256 + f] = (f16)v;
}
// enc/dec embeddings with <P mask
__global__ void k_embx(const int* __restrict__ xs, const int* __restrict__ ys,
                       const float* __restrict__ eemb, const float* __restrict__ demb,
                       f16* __restrict__ xo, f16* __restrict__ yo){
  int id = blockIdx.x; int f = threadIdx.x;  // 2*32*512 blocks x 128
  bool dec = id >= 32*512; int id2 = dec ? id - 32*512 : id;
  int idx = dec ? ys[id2] : xs[id2];
  if (idx < 4) idx = 0;
  const float* src = (dec ? demb : eemb) + (size_t)idx*128;
  (dec ? yo : xo)[(size_t)id2*128 + f] = (f16)src[f];
}

// Whh (1024x256 f32) -> 3-way split for k_lstm2.
// thread mapping: c = tid&3, r = tid>>2; w-index i in [0,1024):
//   element = Whh[(r + 64*(i>>6))*256 + c*64 + (i&63)]
// i <  768           -> Wreg[(i>>3)*256 + tid]        (register-resident)
// 768 <= i < 888     -> Wlds[((i-768)>>3)*256 + tid]  (LDS-resident)
// 888 <= i < 1024    -> Wstr[((i-888)>>3)*256 + tid]  (L2-streamed each step)
__global__ void k_wsplit(const float* __restrict__ Whh, uint4* __restrict__ Wreg,
                         uint4* __restrict__ Wlds, uint4* __restrict__ Wstr){
  const int kb = blockIdx.x;          // 0..127
  const int tid = threadIdx.x;        // 0..255
  const int c = tid & 3, r = tid >> 2;
  f16 tmp[8];
  #pragma unroll
  for (int e8=0; e8<8; e8++){
    int i = kb*8 + e8;
    int row = r + 64*(i>>6);
    int col = c*64 + (i&63);
    tmp[e8] = (f16)Whh[(size_t)row*256 + col];
  }
  uint4 v = *(uint4*)tmp;
  int i0 = kb*8;
  if (i0 < 768)      Wreg[(size_t)(i0>>3)*256 + tid] = v;
  else if (i0 < 888) Wlds[(size_t)((i0-768)>>3)*256 + tid] = v;
  else               Wstr[(size_t)((i0-888)>>3)*256 + tid] = v;
}

// ---------------- GEMM kernels ----------------
__global__ __launch_bounds__(256,4) void k_conv(const f16* __restrict__ epad, const f16* __restrict__ gcT, f16* __restrict__ tf){
  __shared__ f16 lA[64*LDT], lB[64*LDT];
  const int m0 = blockIdx.x*64, n0 = blockIdx.y*64;
  const int b = m0 >> 9, n = m0 & 511;
  f32x4 acc[4]; ZERO4(acc);
  gemm64(epad + ((size_t)b*516 + n)*256, 256, gcT + (size_t)n0*1280, 1280, 1280, lA, lB, acc);
  const int lane=threadIdx.x&63, wv=threadIdx.x>>6, l15=lane&15, kq=lane>>4;
  #pragma unroll
  for (int nt=0;nt<4;nt++)
    #pragma unroll
    for (int r=0;r<4;r++)
      tf[(size_t)(m0 + 16*wv + 4*kq + r)*256 + n0 + nt*16 + l15] = (f16)tanh_c(acc[nt][r]);
}

__global__ __launch_bounds__(256,4) void k_u(const f16* __restrict__ X, const f16* __restrict__ Wih,
                                             const float* __restrict__ bias, f16* __restrict__ U){
  __shared__ f16 lA[64*LDT], lB[64*LDT];
  const int m0 = blockIdx.x*64, n0 = blockIdx.y*64;
  f32x4 acc[4]; ZERO4(acc);
  gemm64(X + (size_t)m0*128, 128, Wih + (size_t)n0*128, 128, 128, lA, lB, acc);
  const int lane=threadIdx.x&63, wv=threadIdx.x>>6, l15=lane&15, kq=lane>>4;
  #pragma unroll
  for (int nt=0;nt<4;nt++){
    float bv = bias[n0 + nt*16 + l15];
    #pragma unroll
    for (int r=0;r<4;r++)
      U[(size_t)(m0 + 16*wv + 4*kq + r)*1024 + n0 + nt*16 + l15] = (f16)(acc[nt][r] + bv);
  }
}

__global__ __launch_bounds__(256,4) void k_th(const f16* __restrict__ henh, const f16* __restrict__ Tf, f16* __restrict__ Th){
  __shared__ f16 lA[64*LDT], lB[64*LDT];
  const int m0 = blockIdx.x*64, n0 = blockIdx.y*64;
  f32x4 acc[4]; ZERO4(acc);
  gemm64(henh + (size_t)m0*512, 512, Tf + (size_t)n0*512, 512, 512, lA, lB, acc);
  const int lane=threadIdx.x&63, wv=threadIdx.x>>6, l15=lane&15, kq=lane>>4;
  #pragma unroll
  for (int nt=0;nt<4;nt++)
    #pragma unroll
    for (int r=0;r<4;r++)
      Th[(size_t)(m0 + 16*wv + 4*kq + r)*256 + n0 + nt*16 + l15] = (f16)acc[nt][r];
}

// pass1: online row-max + sum-exp of logits = tf @ gdT^T over N=2048 (cols>=2000 masked)
__global__ __launch_bounds__(256,2) void k_pass1(const f16* __restrict__ tf, const f16* __restrict__ gdT,
                                                 float* __restrict__ mxp, float* __restrict__ sep){
  __shared__ f16 lA[64*LDA];
  __shared__ f16 lB[64*LDT];
  __shared__ float mx_s[64], se_s[64];
  const int mt = blockIdx.x, ns = blockIdx.y;
  const int tid = threadIdx.x, lane=tid&63, wv=tid>>6, l15=lane&15, kq=lane>>4;
  {
    const f16* A = tf + (size_t)mt*64*256;
    int row = tid>>2, qq = tid&3;
    #pragma unroll
    for (int c=0;c<8;c++)
      *(f16x8*)(lA + row*LDA + c*32 + qq*8) = *(const f16x8*)(A + (size_t)row*256 + c*32 + qq*8);
  }
  if (tid < 64){ mx_s[tid] = -1e30f; se_s[tid] = 0.f; }
  __syncthreads();
  for (int nc=0; nc<8; nc++){
    const int nbase = ns*512 + nc*64;
    const f16* Bm = gdT + (size_t)nbase*256;
    f32x4 acc[4]; ZERO4(acc);
    for (int k0=0; k0<256; k0+=32){
      __syncthreads();
      stage_tile(Bm + k0, 256, lB);
      __syncthreads();
      f16x8 af = frag_ld(lA + (16*wv + l15)*LDA + k0 + kq*8);
      #pragma unroll
      for (int nt=0; nt<4; nt++){
        f16x8 bf = frag_ld(lB + (16*nt + l15)*LDT + kq*8);
        acc[nt] = __builtin_amdgcn_mfma_f32_16x16x32_f16(af, bf, acc[nt], 0,0,0);
      }
    }
    #pragma unroll
    for (int r=0;r<4;r++){
      float av[4]; float cm = -1e30f;
      #pragma unroll
      for (int nt=0;nt<4;nt++){
        int gcol = nbase + nt*16 + l15;
        float a = (gcol < 2000) ? acc[nt][r] : -1e30f;
        av[nt] = a; cm = fmaxf(cm, a);
      }
      cm = wmax16(cm);
      int rr = 16*wv + 4*kq + r;
      float old = mx_s[rr];
      float nm = fmaxf(old, cm);
      float ss = 0.f;
      #pragma unroll
      for (int nt=0;nt<4;nt++) ss += __expf(av[nt] - nm);
      ss = wsum16(ss);
      if (l15 == 0){
        se_s[rr] = se_s[rr]*__expf(old - nm) + ss;
        mx_s[rr] = nm;
      }
    }
  }
  __syncthreads();
  if (tid < 64){
    mxp[(size_t)ns*16384 + mt*64 + tid] = mx_s[tid];
    sep[(size_t)ns*16384 + mt*64 + tid] = se_s[tid];
  }
}

__global__ void k_comb1(const float* __restrict__ mxp, const float* __restrict__ sep,
                        float* __restrict__ mx, float* __restrict__ se){
  int m = blockIdx.x*256 + threadIdx.x;
  float best = -1e30f;
  #pragma unroll
  for (int k=0;k<4;k++) best = fmaxf(best, mxp[(size_t)k*16384 + m]);
  float s = 0.f;
  #pragma unroll
  for (int k=0;k<4;k++) s += sep[(size_t)k*16384 + m] * __expf(mxp[(size_t)k*16384 + m] - best);
  mx[m] = best; se[m] = s;
}

// pass2: scoresT[b][j][i] = exp(logit(i, ys[b][j]) - mx)/se  via gathered-row GEMM
__global__ __launch_bounds__(256,4) void k_pass2(const f16* __restrict__ tf, const f16* __restrict__ gdT,
                                                 const int* __restrict__ ys, const float* __restrict__ mx,
                                                 const float* __restrict__ se, f16* __restrict__ scT){
  __shared__ f16 lA[64*LDT], lB[64*LDT];
  __shared__ int jv[64];
  const int it = blockIdx.x, jt = blockIdx.y, b = blockIdx.z;
  const int tid = threadIdx.x, lane=tid&63, wv=tid>>6, l15=lane&15, kq=lane>>4;
  if (tid<64) jv[tid] = ys[b*512 + jt*64 + tid];
  const f16* A = tf + ((size_t)b*512 + it*64)*256;
  f32x4 acc[4]; ZERO4(acc);
  for (int k0=0;k0<256;k0+=32){
    __syncthreads();
    stage_tile(A + k0, 256, lA);
    { int row=tid>>2, qq=tid&3;
      *(f16x8*)(lB + row*LDT + qq*8) = *(const f16x8*)(gdT + (size_t)jv[row]*256 + k0 + qq*8); }
    __syncthreads();
    f16x8 af = frag_ld(lA + (16*wv+l15)*LDT + kq*8);
    #pragma unroll
    for (int nt=0;nt<4;nt++){
      f16x8 bf = frag_ld(lB + (16*nt+l15)*LDT + kq*8);
      acc[nt] = __builtin_amdgcn_mfma_f32_16x16x32_f16(af, bf, acc[nt], 0,0,0);
    }
  }
  float mxv[4], rsev[4];
  #pragma unroll
  for (int r=0;r<4;r++){
    int i_ = it*64 + 16*wv + 4*kq + r;
    mxv[r] = mx[b*512 + i_];
    rsev[r] = 1.f / se[b*512 + i_];
  }
  #pragma unroll
  for (int nt=0;nt<4;nt++){
    int j_ = jt*64 + nt*16 + l15;
    #pragma unroll
    for (int r=0;r<4;r++){
      int i_ = it*64 + 16*wv + 4*kq + r;
      scT[((size_t)b*512 + j_)*512 + i_] = (f16)(__expf(acc[nt][r] - mxv[r]) * rsev[r]);
    }
  }
}

// fused eij -> softmax over i -> <scores,align> -> partials (i split in 2)
__global__ __launch_bounds__(256,2) void k_final(const f16* __restrict__ hdec, const f16* __restrict__ Th,
                                                 const f16* __restrict__ scT,
                                                 float* __restrict__ pmx, float* __restrict__ pden, float* __restrict__ pnum){
  __shared__ f16 lA[64*LDA];
  __shared__ f16 lB[64*LDT];
  __shared__ float mx_s[64], den_s[64], num_s[64];
  const int is = blockIdx.x, jt = blockIdx.y, b = blockIdx.z;
  const int tid = threadIdx.x, lane=tid&63, wv=tid>>6, l15=lane&15, kq=lane>>4;
  {
    const f16* A = hdec + ((size_t)b*512 + jt*64)*256;
    int row = tid>>2, qq = tid&3;
    #pragma unroll
    for (int c=0;c<8;c++)
      *(f16x8*)(lA + row*LDA + c*32 + qq*8) = *(const f16x8*)(A + (size_t)row*256 + c*32 + qq*8);
  }
  if (tid<64){ mx_s[tid]=-1e30f; den_s[tid]=0.f; num_s[tid]=0.f; }
  __syncthreads();
  for (int ic=0; ic<4; ic++){
    const int i0 = is*256 + ic*64;
    const f16* Bm = Th + ((size_t)b*512 + i0)*256;
    f32x4 acc[4]; ZERO4(acc);
    for (int k0=0;k0<256;k0+=32){
      __syncthreads();
      stage_tile(Bm + k0, 256, lB);
      __syncthreads();
      f16x8 af = frag_ld(lA + (16*wv+l15)*LDA + k0 + kq*8);
      #pragma unroll
      for (int nt=0;nt<4;nt++){
        f16x8 bf = frag_ld(lB + (16*nt+l15)*LDT + kq*8);
        acc[nt] = __builtin_amdgcn_mfma_f32_16x16x32_f16(af, bf, acc[nt], 0,0,0);
      }
    }
    #pragma unroll
    for (int r=0;r<4;r++){
      int jl = 16*wv + 4*kq + r;
      float av[4]; float cm=-1e30f;
      #pragma unroll
      for (int nt=0;nt<4;nt++){ av[nt]=acc[nt][r]; cm=fmaxf(cm,av[nt]); }
      cm = wmax16(cm);
      float old = mx_s[jl], nm = fmaxf(old, cm);
      float ds=0.f, nsum=0.f;
      const size_t srow = ((size_t)b*512 + jt*64 + jl)*512;
      #pragma unroll
      for (int nt=0;nt<4;nt++){
        float e = __expf(av[nt]-nm);
        float sc = (float)scT[srow + i0 + nt*16 + l15];
        ds += e; nsum += sc*e;
      }
      ds = wsum16(ds); nsum = wsum16(nsum);
      if (l15==0){
        float fac = __expf(old-nm);
        den_s[jl] = den_s[jl]*fac + ds;
        num_s[jl] = num_s[jl]*fac + nsum;
        mx_s[jl] = nm;
      }
    }
  }
  __syncthreads();
  if (tid<64){
    size_t idx = (((size_t)b*512) + jt*64 + tid)*2 + is;
    pmx[idx]=mx_s[tid]; pden[idx]=den_s[tid]; pnum[idx]=num_s[tid];
  }
}

__global__ void k_comb2(const float* __restrict__ pmx, const float* __restrict__ pden,
                        const float* __restrict__ pnum, float* __restrict__ out){
  const int b = blockIdx.x, j = threadIdx.x;    // 32 x 512
  size_t base = ((size_t)b*512 + j)*2;
  float m0=pmx[base], m1=pmx[base+1];
  float m = fmaxf(m0,m1);
  float e0=__expf(m0-m), e1=__expf(m1-m);
  float den = pden[base]*e0 + pden[base+1]*e1;
  float num = pnum[base]*e0 + pnum[base+1]*e1;
  float lp = __logf(num) - __logf(den);
  __shared__ float red[512];
  red[j] = lp;
  __syncthreads();
  for (int st=256; st>0; st>>=1){ if (j<st) red[j]+=red[j+st]; __syncthreads(); }
  if (j==0) atomicAdd(out, -red[0]);
}

// ---------------- LSTM v2: one workgroup per sequence, weights in VGPR+LDS+L2 ----------------
// 256 threads; thread (c=tid&3, r=tid>>2) owns rows {r+64m, m=0..15} x K-chunk [c*64, c*64+64).
// K-chunk partials reduced via shfl_xor(1),(2); hidden unit i=r+64u has all 4 gate rows
// (m = g*4+u) in thread (c=0,r). Recurrence closed by 2 __syncthreads per step.
__global__ __launch_bounds__(256,1) void k_lstm2(
    const f16* __restrict__ U, const uint4* __restrict__ Wreg,
    const uint4* __restrict__ Wlds, const uint4* __restrict__ Wstr,
    u16* __restrict__ hout, float* __restrict__ hTcT,
    u16* __restrict__ hdec0, int nsteps, int mode)
{
  __shared__ uint4 wl[15*256];             // 60 KiB LDS-resident weights
  __shared__ __align__(16) f16 h16[4*72];  // h, chunk stride 72 halves (bank spread, 16B aligned)

  const int tid = threadIdx.x;
  const int c = tid & 3, r = tid >> 2;
  int dir = 0, b = blockIdx.x;
  if (mode == 0){ dir = (b >= 32) ? 1 : 0; b &= 31; }

  // register-resident weights (96 uint4 = 384 VGPRs)
  uint4 w[96];
  #pragma unroll
  for (int k8=0;k8<96;k8++) w[k8] = Wreg[(size_t)k8*256 + tid];
  // LDS-resident weights
  #pragma unroll
  for (int j=0;j<15;j++) wl[j*256 + tid] = Wlds[(size_t)j*256 + tid];

  float cst[4] = {0.f,0.f,0.f,0.f};
  if (mode == 0){
    h16[(tid>>6)*72 + (tid&63)] = (f16)0.f;
  } else {
    h16[(tid>>6)*72 + (tid&63)] = (f16)hTcT[(size_t)b*512 + tid];
    #pragma unroll
    for (int u=0;u<4;u++) cst[u] = hTcT[(size_t)b*512 + 256 + u*64 + r];
  }
  __syncthreads();

  const u16* Uu = (const u16*)U;

  #pragma unroll 1
  for (int t=0; t<nsteps; ++t){
    const int tpos = dir ? (nsteps-1-t) : t;
    const size_t ubase = ((size_t)b*512 + tpos)*1024;

    // stream batch A (s8 0..3) issued early
    uint4 sA[4];
    #pragma unroll
    for (int k=0;k<4;k++) sA[k] = Wstr[(size_t)k*256 + tid];

    // U prefetch (gate rows for this thread's hidden units)
    u16 uv[16];
    #pragma unroll
    for (int g=0;g<4;g++)
      #pragma unroll
      for (int u=0;u<4;u++)
        uv[g*4+u] = Uu[ubase + g*256 + u*64 + r];

    // h fragment for this thread's K-chunk
    uint4 hreg[8];
    #pragma unroll
    for (int q=0;q<8;q++) hreg[q] = *(const uint4*)(h16 + c*72 + q*8);
    __syncthreads();   // everyone has read h(t); safe to overwrite later

    float acc[16];
    #pragma unroll
    for (int m=0;m<16;m++) acc[m]=0.f;

    // register part: i = k8*8, m = k8>>3, q = k8&7
    #pragma unroll
    for (int k8=0;k8<96;k8++){
      const int m = k8>>3, q = k8&7;
      uint4 wv4 = w[k8]; uint4 hh = hreg[q];
      acc[m] = dot2u(wv4.x, hh.x, acc[m]);
      acc[m] = dot2u(wv4.y, hh.y, acc[m]);
      acc[m] = dot2u(wv4.z, hh.z, acc[m]);
      acc[m] = dot2u(wv4.w, hh.w, acc[m]);
    }

    // issue B+C, consume A
    uint4 sB[4], sC[4];
    #pragma unroll
    for (int k=0;k<4;k++) sB[k] = Wstr[(size_t)(4+k)*256 + tid];
    #pragma unroll
    for (int k=0;k<4;k++) sC[k] = Wstr[(size_t)(8+k)*256 + tid];
    #pragma unroll
    for (int k=0;k<4;k++){
      const int i = 888 + 8*k;
      const int m = i>>6, q = (i>>3)&7;
      uint4 wv4 = sA[k]; uint4 hh = hreg[q];
      acc[m] = dot2u(wv4.x, hh.x, acc[m]);
      acc[m] = dot2u(wv4.y, hh.y, acc[m]);
      acc[m] = dot2u(wv4.z, hh.z, acc[m]);
      acc[m] = dot2u(wv4.w, hh.w, acc[m]);
    }

    // LDS part 1 (j 0..7 -> m=12)
    #pragma unroll
    for (int j=0;j<8;j++){
      const int m = 12, q = j&7;
      uint4 wv4 = wl[j*256 + tid]; uint4 hh = hreg[q];
      acc[m] = dot2u(wv4.x, hh.x, acc[m]);
      acc[m] = dot2u(wv4.y, hh.y, acc[m]);
      acc[m] = dot2u(wv4.z, hh.z, acc[m]);
      acc[m] = dot2u(wv4.w, hh.w, acc[m]);
    }

    // issue D, consume B
    uint4 sD[5];
    #pragma unroll
    for (int k=0;k<5;k++) sD[k] = Wstr[(size_t)(12+k)*256 + tid];
    #pragma unroll
    for (int k=0;k<4;k++){
      const int i = 888 + 8*(4+k);
      const int m = i>>6, q = (i>>3)&7;
      uint4 wv4 = sB[k]; uint4 hh = hreg[q];
      acc[m] = dot2u(wv4.x, hh.x, acc[m]);
      acc[m] = dot2u(wv4.y, hh.y, acc[m]);
      acc[m] = dot2u(wv4.z, hh.z, acc[m]);
      acc[m] = dot2u(wv4.w, hh.w, acc[m]);
    }

    // LDS part 2 (j 8..14 -> m=13)
    #pragma unroll
    for (int j=8;j<15;j++){
      const int m = 13, q = j&7;
      uint4 wv4 = wl[j*256 + tid]; uint4 hh = hreg[q];
      acc[m] = dot2u(wv4.x, hh.x, acc[m]);
      acc[m] = dot2u(wv4.y, hh.y, acc[m]);
      acc[m] = dot2u(wv4.z, hh.z, acc[m]);
      acc[m] = dot2u(wv4.w, hh.w, acc[m]);
    }

    // consume C, D
    #pragma unroll
    for (int k=0;k<4;k++){
      const int i = 888 + 8*(8+k);
      const int m = i>>6, q = (i>>3)&7;
      uint4 wv4 = sC[k]; uint4 hh = hreg[q];
      acc[m] = dot2u(wv4.x, hh.x, acc[m]);
      acc[m] = dot2u(wv4.y, hh.y, acc[m]);
      acc[m] = dot2u(wv4.z, hh.z, acc[m]);
      acc[m] = dot2u(wv4.w, hh.w, acc[m]);
    }
    #pragma unroll
    for (int k=0;k<5;k++){
      const int i = 888 + 8*(12+k);
      const int m = i>>6, q = (i>>3)&7;
      uint4 wv4 = sD[k]; uint4 hh = hreg[q];
      acc[m] = dot2u(wv4.x, hh.x, acc[m]);
      acc[m] = dot2u(wv4.y, hh.y, acc[m]);
      acc[m] = dot2u(wv4.z, hh.z, acc[m]);
      acc[m] = dot2u(wv4.w, hh.w, acc[m]);
    }

    // cross-chunk reduce (c = lane&3 partners are in-wave)
    #pragma unroll
    for (int m=0;m<16;m++){
      acc[m] += __shfl_xor(acc[m], 1, 64);
      acc[m] += __shfl_xor(acc[m], 2, 64);
    }

    if (c == 0){
      #pragma unroll
      for (int u=0;u<4;u++){
        const int hid = u*64 + r;
        float zi = acc[0*4+u] + (float)*(const f16*)&uv[0*4+u];
        float zf = acc[1*4+u] + (float)*(const f16*)&uv[1*4+u];
        float zg = acc[2*4+u] + (float)*(const f16*)&uv[2*4+u];
        float zo = acc[3*4+u] + (float)*(const f16*)&uv[3*4+u];
        cst[u] = sigf(zf)*cst[u] + sigf(zi)*tanh_c(zg);
        float h = sigf(zo)*tanh_c(cst[u]);
        f16 hf = (f16)h;
        h16[u*72 + r] = hf;
        if (mode == 0){
          hout[((size_t)b*512 + tpos)*512 + dir*256 + hid] = __builtin_bit_cast(u16, hf);
          if (!dir && t == nsteps-1){
            hdec0[(size_t)b*512*256 + hid] = __builtin_bit_cast(u16, hf);
            hTcT[(size_t)b*512 + hid] = h;
            hTcT[(size_t)b*512 + 256 + hid] = cst[u];
          }
        } else {
          hout[((size_t)b*512 + (t+1))*256 + hid] = __builtin_bit_cast(u16, hf);
        }
      }
    }
    __syncthreads();   // h(t+1) visible
  }
}

// ---------------- host ----------------
extern "C" void kernel_launch(void* const* d_in, const int* in_sizes, int n_in,
                              void* d_out, int out_size, void* d_ws, size_t ws_size,
                              hipStream_t stream)
{
  (void)in_sizes; (void)n_in; (void)out_size;
  const int*   xs    = (const int*)d_in[0];
  const int*   ys    = (const int*)d_in[1];
  const float* gemb  = (const float*)d_in[2];
  const float* gconv = (const float*)d_in[3];
  const float* gdec  = (const float*)d_in[4];
  const float* eemb  = (const float*)d_in[5];
  const float* demb  = (const float*)d_in[6];
  const float* eWih  = (const float*)d_in[7];
  const float* eWhh  = (const float*)d_in[8];
  const float* eb    = (const float*)d_in[9];
  const float* dWih  = (const float*)d_in[10];
  const float* dWhh  = (const float*)d_in[11];
  const float* db    = (const float*)d_in[12];
  const float* Tm    = (const float*)d_in[13];

  char* wsb = (char*)d_ws;
  size_t off = 0;
  auto take = [&](size_t bytes)->char*{ char* p = wsb + off; off += (bytes + 255) & ~(size_t)255; return p; };
  f16* epad  = (f16*)take((size_t)32*516*256*2);
  f16* tf    = (f16*)take((size_t)32*512*256*2);
  f16* xemb  = (f16*)take((size_t)32*512*128*2);
  f16* yemb  = (f16*)take((size_t)32*512*128*2);
  f16* Uenc  = (f16*)take((size_t)32*512*1024*2);
  f16* Udec  = (f16*)take((size_t)32*512*1024*2);
  f16* henh  = (f16*)take((size_t)32*512*512*2);
  f16* hdec  = (f16*)take((size_t)32*512*256*2);
  f16* Th    = (f16*)take((size_t)32*512*256*2);
  f16* scT   = (f16*)take((size_t)32*512*512*2);
  float* mx  = (float*)take((size_t)16384*4);
  float* se  = (float*)take((size_t)16384*4);
  float* mxp = (float*)take((size_t)4*16384*4);
  float* sep = (float*)take((size_t)4*16384*4);
  float* pmx = (float*)take((size_t)32*512*2*4);
  float* pden= (float*)take((size_t)32*512*2*4);
  float* pnum= (float*)take((size_t)32*512*2*4);
  float* hTcT= (float*)take((size_t)32*512*4);
  f16* Wihe  = (f16*)take((size_t)1024*128*2);
  f16* Wihd  = (f16*)take((size_t)1024*128*2);
  f16* Tf    = (f16*)take((size_t)256*512*2);
  f16* gcT   = (f16*)take((size_t)256*1280*2);
  f16* gdT   = (f16*)take((size_t)2048*256*2);
  uint4* Wrege = (uint4*)take((size_t)96*256*16);
  uint4* Wldse = (uint4*)take((size_t)15*256*16);
  uint4* Wstre = (uint4*)take((size_t)17*256*16);
  uint4* Wregd = (uint4*)take((size_t)96*256*16);
  uint4* Wldsd = (uint4*)take((size_t)15*256*16);
  uint4* Wstrd = (uint4*)take((size_t)17*256*16);
  if (off > ws_size) return;  // insufficient scratch -> visible as wrong answer

  hipMemsetAsync(d_out, 0, sizeof(float), stream);

  // weight conversions / splits
  k_cvt<<<dim3(512),  256, 0, stream>>>(eWih, Wihe, 1024*128);
  k_cvt<<<dim3(512),  256, 0, stream>>>(dWih, Wihd, 1024*128);
  k_cvt<<<dim3(512),  256, 0, stream>>>(Tm,   Tf,   256*512);
  k_gconvT<<<dim3(1280), 256, 0, stream>>>(gconv, gcT);
  k_gdecT <<<dim3(2048), 256, 0, stream>>>(gdec, gdT);
  k_wsplit<<<dim3(128), 256, 0, stream>>>(eWhh, Wrege, Wldse, Wstre);
  k_wsplit<<<dim3(128), 256, 0, stream>>>(dWhh, Wregd, Wldsd, Wstrd);

  // embeddings
  k_epad<<<dim3(32*516), 256, 0, stream>>>(xs, gemb, epad);
  k_embx<<<dim3(2*32*512), 128, 0, stream>>>(xs, ys, eemb, demb, xemb, yemb);

  // G-stack
  k_conv<<<dim3(256,4), 256, 0, stream>>>(epad, gcT, tf);
  k_pass1<<<dim3(256,4), 256, 0, stream>>>(tf, gdT, mxp, sep);
  k_comb1<<<dim3(64), 256, 0, stream>>>(mxp, sep, mx, se);
  k_pass2<<<dim3(8,8,32), 256, 0, stream>>>(tf, gdT, ys, mx, se, scT);

  // LSTM input-gate precompute
  k_u<<<dim3(256,16), 256, 0, stream>>>(xemb, Wihe, eb, Uenc);
  k_u<<<dim3(256,16), 256, 0, stream>>>(yemb, Wihd, db, Udec);

  // recurrences (single-WG per sequence; no cross-CU sync)
  k_lstm2<<<dim3(64), 256, 0, stream>>>(Uenc, Wrege, Wldse, Wstre, (u16*)henh, hTcT, (u16*)hdec, 512, 0);
  k_lstm2<<<dim3(32), 256, 0, stream>>>(Udec, Wregd, Wldsd, Wstrd, (u16*)hdec, hTcT, (u16*)hdec, 511, 1);

  // alignment
  k_th<<<dim3(256,4), 256, 0, stream>>>(henh, Tf, Th);
  k_final<<<dim3(2,8,32), 256, 0, stream>>>(hdec, Th, scT, pmx, pden, pnum);
  k_comb2<<<dim3(32), 512, 0, stream>>>(pmx, pden, pnum, (float*)d_out);
}